// Round 6
// baseline (229.609 us; speedup 1.0000x reference)
//
#include <hip/hip_runtime.h>
#include <hip/hip_bf16.h>

// R6: dispatch-count reduction 14 -> 10. R5 left no dominant kernel (<43us
// each, profile topped by harness re-poison fills); work-sum ~120us vs 216us
// measured => ~80-100us is serial launch overhead/gaps. Fusions (independent
// block-range unions only): k_front = cvt U histp U {bnsum/cnss zero +
// view0-sumsq from raw emb} (kills memset + cvt atomics); k_abf_xf1 = abfrc U
// xf2-L1; k_xf2 gains fromPart staging (inline partial-combine+tanh) killing
// k_comb1 and the h1agg round-trip.

#define NN    1195
#define NUSER 805
#define NITEM 390
#define DD    64
#define BB    2048
#define NPAD  1216          // 19*64, padded node/k count
#define E_TOT 1000000
#define E_SUB 500000
#define MT    19            // m-tiles per graph
#define KT    8             // K-split factor
#define CHUNK 3             // ceil(19/8) k-subtiles per block
#define LSTR  72            // LDS row stride in bf16 elems
#define OUT2STRIDE (NN*DD)
#define CPG    299          // comb blocks per graph = ceil(1195*64/256)
#define P8W    152          // u32 words per histogram row (1216 u4 cells)
#define ROWS   96           // histogram rows per block (57KB LDS)
#define RB     13           // ceil(NN/ROWS)
#define FNT    13           // k_final col tiles = ceil(805/64)
#define KPAD   448          // esynd padded K (7*64)
#define ENT    7            // esynd k-steps

typedef unsigned int uint;
typedef unsigned short u16;
typedef unsigned char u8;
typedef __attribute__((ext_vector_type(8))) short short8;
typedef __attribute__((ext_vector_type(4))) float f32x4;

__device__ __forceinline__ float wsum(float v) {
#pragma unroll
    for (int m = 32; m > 0; m >>= 1) v += __shfl_xor(v, m, 64);
    return v;
}
__device__ __forceinline__ u16 f2b(float f) {           // fp32 -> bf16 RNE bits
    uint u = __float_as_uint(f);
    return (u16)((u + 0x7FFFu + ((u >> 16) & 1u)) >> 16);
}
__device__ __forceinline__ float b2f16(u16 b) { return __uint_as_float(((uint)b) << 16); }
__device__ __forceinline__ void split4(const float* v, u16* hh, u16* ll) {
#pragma unroll
    for (int j = 0; j < 4; ++j) {
        u16 h = f2b(v[j]);
        hh[j] = h;
        ll[j] = f2b(v[j] - b2f16(h));
    }
}
__device__ __forceinline__ uint2 pack4(const u16* x) {
    uint2 o;
    o.x = (uint)x[0] | ((uint)x[1] << 16);
    o.y = (uint)x[2] | ((uint)x[3] << 16);
    return o;
}

// ---- converted-input layout (floats, relative to OFF_CVT) ----
#define CVT_EMB   0
#define CVT_W1    76480
#define CVT_B1    80576
#define CVT_W2    80640
#define CVT_B2    84736
#define CVT_MLPW  84800
#define CVT_MLPB  88896
#define CVT_GAMMA 88960
#define CVT_BETA  89024
#define CVT_TOTAL 89088

// ---------------- workspace layout (floats) ----------------
constexpr size_t alignUp64(size_t x) { return (x + 63) & ~size_t(63); }
constexpr size_t OFF_BNS  = 0;                                        // [128]
constexpr size_t OFF_CNSS = 128;                                      // [256]
constexpr size_t OFF_FLAG = 384;                                      // [16]
constexpr size_t OFF_CVT  = 448;                                      // [CVT_TOTAL]
constexpr size_t OFF_ABF  = alignUp64(OFF_CVT + CVT_TOTAL);           // bf16 A 3*NN*NPAD u16
constexpr size_t OFF_RC   = alignUp64(OFF_ABF + (3ull * NN * NPAD) / 2);
constexpr size_t OFF_POOL = alignUp64(OFF_RC + 3ull * NPAD);
constexpr size_t OFF_PART = OFF_POOL;                                 // fp32 partials KT*3*NPAD*64
constexpr size_t OFF_H1   = alignUp64(OFF_PART + (size_t)KT * 3 * NPAD * 64);
constexpr size_t OFF_H2   = alignUp64(OFF_H1 + 64ull * NPAD);
constexpr size_t OFF_OUT2 = alignUp64(OFF_H2 + 3ull * 64 * NPAD);
constexpr size_t OFF_CU   = alignUp64(OFF_OUT2 + 3ull * NN * DD);     // [448*64]
constexpr size_t OFF_CI   = alignUp64(OFF_CU + 448ull * DD);
constexpr size_t OFF_H    = alignUp64(OFF_CI + (size_t)NUSER * DD);
constexpr size_t POOL_END = alignUp64(OFF_H + (size_t)BB * DD);
// P8 and later cuWT hi/lo alias the pool at OFF_POOL/OFF_PART (dead by then).

// ---------------- kernels ----------------

// FUSED front: [0,HB) histogram blocks; HB = stats block (zero bnsum/cnss +
// view-0 user col-sumsq from RAW emb); (HB, ...] input-convert blocks.
__global__ __launch_bounds__(512) void k_front(const void* presc, const void* emb,
        const void* p1, const void* p2, const void* p3, const void* p4,
        const void* p5, const void* p6, const void* p7, const void* p8, const void* p9,
        const int* __restrict__ tg, const int* __restrict__ s1, const int* __restrict__ s2,
        float* __restrict__ dst, float* __restrict__ cnss, float* __restrict__ bnsum,
        int* __restrict__ flag, uint* __restrict__ P8, int S, int HB) {
    __shared__ __align__(16) uint lds[ROWS * P8W];
    int b = blockIdx.x, t = threadIdx.x;
    int isbf = (((const u16*)presc)[0] == 0x3F80u) ? 1 : 0;   // presc[0][0]==1.0 always
    if (b < HB) {
        // ---- LDS-bucketed u4 partial histogram ----
        int p = b % S;
        int rg = b / S;
        int r = rg % RB;
        int g = rg / RB;
        int r0 = r * ROWS;
        {
            uint4* l4 = (uint4*)lds;
            for (int i = t; i < (ROWS * P8W) >> 2; i += 512) l4[i] = (uint4){0u, 0u, 0u, 0u};
        }
        __syncthreads();
        const int* eg = (g == 0) ? tg : (g == 1 ? s1 : s2);
        int Eg = (g == 0) ? E_TOT : E_SUB;
        int e0 = (int)(((long)p * Eg / S) & ~3L);
        int e1 = (p == S - 1) ? Eg : (int)(((long)(p + 1) * Eg / S) & ~3L);
        const int* srcp = eg;
        const int* dstp = eg + Eg;
        for (int i = e0 + t * 4; i < e1; i += 512 * 4) {
            int4 d4 = *(const int4*)(dstp + i);
            int4 s4 = *(const int4*)(srcp + i);
            int rw;
            rw = d4.x - r0; if ((unsigned)rw < ROWS) atomicAdd(&lds[rw * P8W + (s4.x >> 3)], 1u << ((s4.x & 7) * 4));
            rw = d4.y - r0; if ((unsigned)rw < ROWS) atomicAdd(&lds[rw * P8W + (s4.y >> 3)], 1u << ((s4.y & 7) * 4));
            rw = d4.z - r0; if ((unsigned)rw < ROWS) atomicAdd(&lds[rw * P8W + (s4.z >> 3)], 1u << ((s4.z & 7) * 4));
            rw = d4.w - r0; if ((unsigned)rw < ROWS) atomicAdd(&lds[rw * P8W + (s4.w >> 3)], 1u << ((s4.w & 7) * 4));
        }
        __syncthreads();
        int rmax = ROWS; if (r0 + rmax > NN) rmax = NN - r0;
        uint* out = P8 + ((size_t)p * 3 + g) * NN * P8W + (size_t)r0 * P8W;
        int n4 = (rmax * P8W) >> 2;
        const uint4* l4 = (const uint4*)lds;
        uint4* o4 = (uint4*)out;
        for (int i = t; i < n4; i += 512) o4[i] = l4[i];
    } else if (b == HB) {
        // ---- stats block: zero accumulators + view-0 user column sumsq ----
        for (int i = t; i < 192; i += 512) cnss[64 + i] = 0.0f;
        if (t < 128) bnsum[t] = 0.0f;
        int c = t & 63, chunk = t >> 6;            // 8 row-chunks
        float s = 0.0f;
        const u16* e16 = (const u16*)emb;
        const float* e32 = (const float*)emb;
        for (int r = chunk; r < NUSER; r += 8) {
            float v = isbf ? b2f16(e16[r * 64 + c]) : e32[r * 64 + c];
            s = fmaf(v, v, s);
        }
        float* sd = (float*)lds;
        sd[t] = s;
        __syncthreads();
        if (t < 64) {
            float tot = 0.0f;
#pragma unroll
            for (int j = 0; j < 8; ++j) tot += sd[j * 64 + t];
            cnss[t] = tot;
        }
    } else {
        // ---- input convert (bf16|f32 -> f32) ----
        int i = (b - HB - 1) * 512 + t;
        if (i == 0) *flag = isbf;
        if (i < CVT_TOTAL) {
            const void* s2p; int o2;
            if      (i < CVT_W1)    { s2p = p1; o2 = i; }
            else if (i < CVT_B1)    { s2p = p2; o2 = i - CVT_W1; }
            else if (i < CVT_W2)    { s2p = p3; o2 = i - CVT_B1; }
            else if (i < CVT_B2)    { s2p = p4; o2 = i - CVT_W2; }
            else if (i < CVT_MLPW)  { s2p = p5; o2 = i - CVT_B2; }
            else if (i < CVT_MLPB)  { s2p = p6; o2 = i - CVT_MLPW; }
            else if (i < CVT_GAMMA) { s2p = p7; o2 = i - CVT_MLPB; }
            else if (i < CVT_BETA)  { s2p = p8; o2 = i - CVT_GAMMA; }
            else                    { s2p = p9; o2 = i - CVT_BETA; }
            dst[i] = isbf ? __bfloat162float(((const __hip_bfloat16*)s2p)[o2])
                          : ((const float*)s2p)[o2];
        }
    }
}

// shared MFMA transform body: Hout[d][col] = sum_k W[d][k]*x[col][k] (+bias),
// transposed bf16 hi/lo planes. fromPart: x row = tanh(sum_kt part * rcnt).
__device__ __forceinline__ void xf2_body(int g, int n0, int t,
        const float* xsrc, size_t xgstride,
        const float* part, const float* rcnt, int fromPart, int rowlim,
        const float* W, const float* bias,
        u16* Hhi, u16* Hlo, size_t hgstride, int ostride,
        u16* Ah, u16* Al, u16* Bh, u16* Bl, float* bs) {
    int w = t >> 6, l = t & 63;
    if (t < 64) bs[t] = bias ? bias[t] : 0.0f;
    int r = t >> 2, c0 = (t & 3) * 16;
    {
        const float* Wr = W + r * 64 + c0;
        float av[16];
#pragma unroll
        for (int j4 = 0; j4 < 4; ++j4) {
            float4 v = *(const float4*)(Wr + j4 * 4);
            av[j4*4+0] = v.x; av[j4*4+1] = v.y; av[j4*4+2] = v.z; av[j4*4+3] = v.w;
        }
#pragma unroll
        for (int j4 = 0; j4 < 4; ++j4) {
            u16 hh[4], ll[4];
            split4(av + j4*4, hh, ll);
            *(uint2*)(Ah + r * LSTR + c0 + j4*4) = pack4(hh);
            *(uint2*)(Al + r * LSTR + c0 + j4*4) = pack4(ll);
        }
    }
    {
        int node = n0 + r;
        float xr[16];
#pragma unroll
        for (int j = 0; j < 16; ++j) xr[j] = 0.0f;
        if (node < rowlim) {
            if (fromPart) {
#pragma unroll
                for (int k = 0; k < KT; ++k) {
                    const float* pp = part + (((size_t)k * 3 + g) * NPAD + node) * 64 + c0;
#pragma unroll
                    for (int j4 = 0; j4 < 4; ++j4) {
                        float4 v = *(const float4*)(pp + j4 * 4);
                        xr[j4*4+0] += v.x; xr[j4*4+1] += v.y;
                        xr[j4*4+2] += v.z; xr[j4*4+3] += v.w;
                    }
                }
                float rc = rcnt[g * NPAD + node];
#pragma unroll
                for (int j = 0; j < 16; ++j) xr[j] = tanhf(xr[j] * rc);
            } else {
                const float* Xr = xsrc + xgstride * g + (size_t)node * 64 + c0;
#pragma unroll
                for (int j4 = 0; j4 < 4; ++j4) {
                    float4 v = *(const float4*)(Xr + j4 * 4);
                    xr[j4*4+0] = v.x; xr[j4*4+1] = v.y;
                    xr[j4*4+2] = v.z; xr[j4*4+3] = v.w;
                }
            }
        }
#pragma unroll
        for (int j4 = 0; j4 < 4; ++j4) {
            u16 hh[4], ll[4];
            split4(xr + j4*4, hh, ll);
            *(uint2*)(Bh + r * LSTR + c0 + j4*4) = pack4(hh);
            *(uint2*)(Bl + r * LSTR + c0 + j4*4) = pack4(ll);
        }
    }
    __syncthreads();
    f32x4 acc[4];
#pragma unroll
    for (int p = 0; p < 4; ++p) acc[p] = (f32x4){0.f, 0.f, 0.f, 0.f};
    int mrow = w * 16 + (l & 15);
    int q8 = (l >> 4) * 8;
#pragma unroll
    for (int ks = 0; ks < 2; ++ks) {
        short8 ah = *(const short8*)(Ah + mrow * LSTR + ks * 32 + q8);
        short8 al = *(const short8*)(Al + mrow * LSTR + ks * 32 + q8);
#pragma unroll
        for (int p = 0; p < 4; ++p) {
            int nrow = p * 16 + (l & 15);
            short8 bh = *(const short8*)(Bh + nrow * LSTR + ks * 32 + q8);
            short8 bl = *(const short8*)(Bl + nrow * LSTR + ks * 32 + q8);
            acc[p] = __builtin_amdgcn_mfma_f32_16x16x32_bf16(ah, bh, acc[p], 0, 0, 0);
            acc[p] = __builtin_amdgcn_mfma_f32_16x16x32_bf16(ah, bl, acc[p], 0, 0, 0);
            acc[p] = __builtin_amdgcn_mfma_f32_16x16x32_bf16(al, bh, acc[p], 0, 0, 0);
        }
    }
    int q = l >> 4;
#pragma unroll
    for (int p = 0; p < 4; ++p) {
        int node = n0 + p * 16 + (l & 15);
#pragma unroll
        for (int rr2 = 0; rr2 < 4; ++rr2) {
            int d = w * 16 + q * 4 + rr2;
            float v = acc[p][rr2] + bs[d];
            u16 h = f2b(v);
            size_t o = hgstride * g + (size_t)d * ostride + node;
            Hhi[o] = h;
            Hlo[o] = f2b(v - b2f16(h));
        }
    }
}

// standalone xf2 (L2 fromPart; cuWT)
__global__ __launch_bounds__(256) void k_xf2(const float* __restrict__ xsrc,
        size_t xgstride, const float* __restrict__ part, const float* __restrict__ rcnt,
        int fromPart, int ngb, int rowlim,
        const float* __restrict__ W, const float* __restrict__ bias,
        u16* __restrict__ Hhi, u16* __restrict__ Hlo, size_t hgstride, int ostride) {
    __shared__ u16 Ah[64 * LSTR], Al[64 * LSTR], Bh[64 * LSTR], Bl[64 * LSTR];
    __shared__ float bs[64];
    int b = blockIdx.x;
    xf2_body(b / ngb, (b % ngb) * 64, threadIdx.x, xsrc, xgstride, part, rcnt,
             fromPart, rowlim, W, bias, Hhi, Hlo, hgstride, ostride,
             Ah, Al, Bh, Bl, bs);
}

// FUSED: [0,3*NN) = merge S u4 partial histograms -> bf16 A + 1/deg;
// [3*NN, 3*NN+MT) = xf2 layer-1 (emb @ W1^T + b1). Independent work.
__global__ __launch_bounds__(256) void k_abf_xf1(const uint* __restrict__ P8, int S,
        u16* __restrict__ Abf, float* __restrict__ rcnt,
        const float* __restrict__ embF, const float* __restrict__ W1,
        const float* __restrict__ b1, u16* __restrict__ H1hi, u16* __restrict__ H1lo) {
    __shared__ u16 Ah[64 * LSTR], Al[64 * LSTR], Bh[64 * LSTR], Bl[64 * LSTR];
    __shared__ float bs[64];
    __shared__ float ws4[4];
    int b = blockIdx.x, t = threadIdx.x;
    if (b < 3 * NN) {
        int g = b / NN, m = b % NN;
        int w = t >> 6;
        float partial = 0.0f;
        if (t < P8W) {
            uint cnt[8] = {0, 0, 0, 0, 0, 0, 0, 0};
            for (int p = 0; p < S; ++p) {
                uint v = P8[(((size_t)p * 3 + g) * NN + m) * P8W + t];
#pragma unroll
                for (int k = 0; k < 8; ++k) cnt[k] += (v >> (4 * k)) & 15u;
            }
            uint4 o;
            o.x = (uint)f2b((float)cnt[0]) | ((uint)f2b((float)cnt[1]) << 16);
            o.y = (uint)f2b((float)cnt[2]) | ((uint)f2b((float)cnt[3]) << 16);
            o.z = (uint)f2b((float)cnt[4]) | ((uint)f2b((float)cnt[5]) << 16);
            o.w = (uint)f2b((float)cnt[6]) | ((uint)f2b((float)cnt[7]) << 16);
            *(uint4*)(Abf + (size_t)b * NPAD + t * 8) = o;
#pragma unroll
            for (int k = 0; k < 8; ++k) partial += (float)cnt[k];
        }
        partial = wsum(partial);
        if ((t & 63) == 0) ws4[w] = partial;
        __syncthreads();
        if (t == 0)
            rcnt[g * NPAD + m] = 1.0f / fmaxf(ws4[0] + ws4[1] + ws4[2] + ws4[3], 1.0f);
    } else {
        int nt = b - 3 * NN;
        xf2_body(0, nt * 64, t, embF, 0, nullptr, nullptr, 0, NN, W1, b1,
                 H1hi, H1lo, 0, NPAD, Ah, Al, Bh, Bl, bs);
    }
}

// MFMA aggregation with split-bf16 B; K-split partials
__global__ __launch_bounds__(256) void k_aggp(const u16* __restrict__ Abf,
        const u16* __restrict__ Hhi, const u16* __restrict__ Hlo, size_t hstride,
        float* __restrict__ part) {
    int b = blockIdx.x;
    int kt = b & 7;
    int mt = (b >> 3) % MT;
    int g  = (b >> 3) / MT;
    int t = threadIdx.x, w = t >> 6, l = t & 63;
    __shared__ u16 As[64 * LSTR], Bh[64 * LSTR], Bl[64 * LSTR];
    f32x4 acc[4];
#pragma unroll
    for (int p = 0; p < 4; ++p) acc[p] = (f32x4){0.f, 0.f, 0.f, 0.f};
    int m0 = mt * 64;
    const u16* Ag = Abf + (size_t)g * NN * NPAD;
    const u16* Hg = Hhi + hstride * g;
    const u16* Lg = Hlo + hstride * g;
    int st0 = kt * CHUNK;
    int st1 = st0 + CHUNK; if (st1 > MT) st1 = MT;
    int rr = t >> 4, c4 = (t & 15) * 4;
    for (int st = st0; st < st1; ++st) {
        int s0 = st * 64;
        __syncthreads();
#pragma unroll
        for (int pass = 0; pass < 4; ++pass) {
            int r = pass * 16 + rr;
            uint2 av = {0u, 0u};
            if (m0 + r < NN) av = *(const uint2*)(Ag + (size_t)(m0 + r) * NPAD + s0 + c4);
            *(uint2*)(As + r * LSTR + c4) = av;
            *(uint2*)(Bh + r * LSTR + c4) = *(const uint2*)(Hg + (size_t)r * NPAD + s0 + c4);
            *(uint2*)(Bl + r * LSTR + c4) = *(const uint2*)(Lg + (size_t)r * NPAD + s0 + c4);
        }
        __syncthreads();
        int mrow = w * 16 + (l & 15);
        int q8 = (l >> 4) * 8;
#pragma unroll
        for (int ks = 0; ks < 2; ++ks) {
            short8 a = *(const short8*)(As + mrow * LSTR + ks * 32 + q8);
#pragma unroll
            for (int p = 0; p < 4; ++p) {
                int nrow = p * 16 + (l & 15);
                short8 bh = *(const short8*)(Bh + nrow * LSTR + ks * 32 + q8);
                short8 bl = *(const short8*)(Bl + nrow * LSTR + ks * 32 + q8);
                acc[p] = __builtin_amdgcn_mfma_f32_16x16x32_bf16(a, bh, acc[p], 0, 0, 0);
                acc[p] = __builtin_amdgcn_mfma_f32_16x16x32_bf16(a, bl, acc[p], 0, 0, 0);
            }
        }
    }
    int q = l >> 4;
#pragma unroll
    for (int p = 0; p < 4; ++p) {
        int n = p * 16 + (l & 15);
#pragma unroll
        for (int r = 0; r < 4; ++r) {
            int m = m0 + w * 16 + q * 4 + r;
            if (m < NN)
                part[(((size_t)kt * 3 + g) * NPAD + m) * 64 + n] = acc[p][r];
        }
    }
}

// layer-2 combine + views-1..3 user column sumsq accumulation
__global__ __launch_bounds__(256) void k_comb(const float* __restrict__ part,
        const float* __restrict__ rcnt, float* __restrict__ out, float* __restrict__ cnss) {
    int g = blockIdx.x / CPG, bi = blockIdx.x % CPG;
    int t = threadIdx.x;
    int idx = bi * 256 + t;                 // within graph
    int m = idx >> 6, n = idx & 63;
    bool valid = idx < NN * 64;
    float v = 0.0f;
    if (valid) {
        float s = 0.0f;
#pragma unroll
        for (int k = 0; k < KT; ++k)
            s += part[(((size_t)k * 3 + g) * NPAD + m) * 64 + n];
        v = tanhf(s * rcnt[g * NPAD + m]);
        out[(size_t)g * NN * 64 + idx] = v;
    }
    float x2 = (valid && m < NUSER) ? v * v : 0.0f;
    __shared__ float sd[256];
    sd[t] = x2;
    __syncthreads();
    if (t < 64) {
        float s = sd[t] + sd[t + 64] + sd[t + 128] + sd[t + 192];
        if (s != 0.0f) atomicAdd(&cnss[(g + 1) * 64 + t], s);
    }
}

// cu (item rows, 4-view row-norm fusion) + ci (user rows, 4-view col-norm fusion)
__global__ void k_cuci(const float* __restrict__ embf, const float* __restrict__ out2,
                       const float* __restrict__ cnss, float* __restrict__ cu,
                       float* __restrict__ ci) {
    int b = blockIdx.x, l = threadIdx.x;
    if (b < 448) {
        if (b >= NITEM) { cu[(size_t)b * DD + l] = 0.0f; return; }
        int node = NUSER + b;
        const float* v0 = embf + (size_t)node * DD;
        const float* v1 = out2 + (size_t)node * DD;
        const float* v2 = out2 + OUT2STRIDE + (size_t)node * DD;
        const float* v3 = out2 + 2ull * OUT2STRIDE + (size_t)node * DD;
        float total = 0.0f;
        { float x = v0[l]; float ss = wsum(x * x); total += x / sqrtf(ss); }
        { float x = v1[l]; float ss = wsum(x * x); total += x / sqrtf(ss); }
        { float x = v2[l]; float ss = wsum(x * x); total += x / sqrtf(ss); }
        { float x = v3[l]; float ss = wsum(x * x); total += x / sqrtf(ss); }
        cu[(size_t)b * DD + l] = 0.25f * total;
    } else {
        int u = b - 448;
        size_t i = (size_t)u * DD + l;
        float s = embf[i] / sqrtf(cnss[l])
                + out2[i] / sqrtf(cnss[64 + l])
                + out2[OUT2STRIDE + i] / sqrtf(cnss[128 + l])
                + out2[2ull * OUT2STRIDE + i] / sqrtf(cnss[192 + l]);
        ci[i] = 0.25f * s;
    }
}

// h_pre = (presc @ cuWT^T)/rowsum + bias via MFMA; rowsum from ones-column MFMA;
// + BN partial sums.
__global__ __launch_bounds__(256) void k_esynd(const void* __restrict__ presc,
        const u16* __restrict__ cwh, const u16* __restrict__ cwl,
        const float* __restrict__ mlpB, const int* __restrict__ flag,
        float* __restrict__ hpre, float* __restrict__ bnsum) {
    int m0 = blockIdx.x * 64;
    int t = threadIdx.x, w = t >> 6, l = t & 63;
    int isbf = *flag;
    const u16* pB = (const u16*)presc;
    const float* pF = (const float*)presc;
    __shared__ u16 As[64 * LSTR], Bh[64 * LSTR], Bl[64 * LSTR];
    __shared__ u16 Ones[16 * LSTR];
    __shared__ float bs[64];
    __shared__ float r1[4][64], r2[4][64];
    for (int i = t; i < 16 * LSTR; i += 256) Ones[i] = (i < 64) ? 0x3F80u : 0u;
    if (t < 64) bs[t] = mlpB[t];

    f32x4 acc[4], acc1;
#pragma unroll
    for (int p = 0; p < 4; ++p) acc[p] = (f32x4){0.f, 0.f, 0.f, 0.f};
    acc1 = (f32x4){0.f, 0.f, 0.f, 0.f};

    int rr = t >> 4, c4 = (t & 15) * 4;
    for (int st = 0; st < ENT; ++st) {
        int s0 = st * 64;
        __syncthreads();
#pragma unroll
        for (int pass = 0; pass < 4; ++pass) {
            int r = pass * 16 + rr;
            int m = m0 + r;
            int kb = s0 + c4;
            u16 a4[4];
            if (kb + 3 < NITEM) {
                if (isbf) {
                    const uint* p32 = (const uint*)pB + (((size_t)m * NITEM + kb) >> 1);
                    uint u0 = p32[0], u1 = p32[1];
                    a4[0] = (u16)u0; a4[1] = (u16)(u0 >> 16);
                    a4[2] = (u16)u1; a4[3] = (u16)(u1 >> 16);
                } else {
                    const float2* pf2 = (const float2*)(pF + (size_t)m * NITEM + kb);
                    float2 f0 = pf2[0], f1 = pf2[1];
                    a4[0] = f2b(f0.x); a4[1] = f2b(f0.y);
                    a4[2] = f2b(f1.x); a4[3] = f2b(f1.y);
                }
            } else {
#pragma unroll
                for (int j = 0; j < 4; ++j) {
                    int k = kb + j;
                    a4[j] = (k < NITEM)
                          ? (isbf ? pB[(size_t)m * NITEM + k] : f2b(pF[(size_t)m * NITEM + k]))
                          : (u16)0;
                }
            }
            uint2 o;
            o.x = (uint)a4[0] | ((uint)a4[1] << 16);
            o.y = (uint)a4[2] | ((uint)a4[3] << 16);
            *(uint2*)(As + r * LSTR + c4) = o;
            *(uint2*)(Bh + r * LSTR + c4) = *(const uint2*)(cwh + (size_t)r * KPAD + s0 + c4);
            *(uint2*)(Bl + r * LSTR + c4) = *(const uint2*)(cwl + (size_t)r * KPAD + s0 + c4);
        }
        __syncthreads();
        int mrow = w * 16 + (l & 15);
        int q8 = (l >> 4) * 8;
#pragma unroll
        for (int ks = 0; ks < 2; ++ks) {
            short8 a = *(const short8*)(As + mrow * LSTR + ks * 32 + q8);
            short8 on = *(const short8*)(Ones + (l & 15) * LSTR + ks * 32 + q8);
            acc1 = __builtin_amdgcn_mfma_f32_16x16x32_bf16(a, on, acc1, 0, 0, 0);
#pragma unroll
            for (int p = 0; p < 4; ++p) {
                int nrow = p * 16 + (l & 15);
                short8 bh = *(const short8*)(Bh + nrow * LSTR + ks * 32 + q8);
                short8 bl = *(const short8*)(Bl + nrow * LSTR + ks * 32 + q8);
                acc[p] = __builtin_amdgcn_mfma_f32_16x16x32_bf16(a, bh, acc[p], 0, 0, 0);
                acc[p] = __builtin_amdgcn_mfma_f32_16x16x32_bf16(a, bl, acc[p], 0, 0, 0);
            }
        }
    }
    float inv[4];
#pragma unroll
    for (int r = 0; r < 4; ++r)
        inv[r] = 1.0f / __shfl(acc1[r], l & 48, 64);
    int q = l >> 4;
#pragma unroll
    for (int p = 0; p < 4; ++p) {
        int col = p * 16 + (l & 15);
        float a = 0.0f, c = 0.0f;
#pragma unroll
        for (int r = 0; r < 4; ++r) {
            float hv = acc[p][r] * inv[r] + bs[col];
            hpre[(size_t)(m0 + w * 16 + q * 4 + r) * DD + col] = hv;
            a += hv; c = fmaf(hv, hv, c);
        }
        a += __shfl_xor(a, 16, 64); a += __shfl_xor(a, 32, 64);
        c += __shfl_xor(c, 16, 64); c += __shfl_xor(c, 32, 64);
        if (l < 16) { r1[w][col] = a; r2[w][col] = c; }
    }
    __syncthreads();
    if (t < 64) {
        atomicAdd(&bnsum[t],      r1[0][t] + r1[1][t] + r1[2][t] + r1[3][t]);
        atomicAdd(&bnsum[64 + t], r2[0][t] + r2[1][t] + r2[2][t] + r2[3][t]);
    }
}

// pre = relu(BN(h_pre)) @ ci^T via MFMA 64x64 tiles, bf16 hi/lo both operands.
__global__ __launch_bounds__(256) void k_final(const float* __restrict__ hpre,
        const float* __restrict__ bnsum, const float* __restrict__ gamma,
        const float* __restrict__ beta, const float* __restrict__ ci,
        void* __restrict__ out, const int* __restrict__ flag) {
    int b = blockIdx.x;
    int mt = b / FNT, nt = b % FNT;
    int m0 = mt * 64, n0 = nt * 64;
    int t = threadIdx.x, w = t >> 6, l = t & 63;
    __shared__ u16 Ah[64 * LSTR], Al[64 * LSTR], Bh[64 * LSTR], Bl[64 * LSTR];
    __shared__ float mn[64], rsg[64], bt[64];
    if (t < 64) {
        float mean = bnsum[t] * (1.0f / BB);
        float var = bnsum[64 + t] * (1.0f / BB) - mean * mean;
        mn[t] = mean;
        rsg[t] = gamma[t] / sqrtf(var + 1e-5f);
        bt[t] = beta[t];
    }
    __syncthreads();
    const float4* hp4 = (const float4*)(hpre + (size_t)m0 * 64);
    const float4* ci4 = (const float4*)ci;
#pragma unroll
    for (int k = 0; k < 4; ++k) {
        int i = t + k * 256;
        int r = i >> 4, c4 = (i & 15) * 4;
        float4 v = hp4[i];
        float vv[4] = {v.x, v.y, v.z, v.w};
        u16 hh[4], ll[4];
#pragma unroll
        for (int j = 0; j < 4; ++j) {
            int d = c4 + j;
            float x = fmaxf((vv[j] - mn[d]) * rsg[d] + bt[d], 0.0f);
            u16 hb = f2b(x);
            hh[j] = hb;
            ll[j] = f2b(x - b2f16(hb));
        }
        *(uint2*)(Ah + r * LSTR + c4) = pack4(hh);
        *(uint2*)(Al + r * LSTR + c4) = pack4(ll);
        int col = n0 + r;
        float4 cv = (col < NUSER) ? ci4[(size_t)col * 16 + (i & 15)]
                                  : (float4){0.f, 0.f, 0.f, 0.f};
        float cc[4] = {cv.x, cv.y, cv.z, cv.w};
        split4(cc, hh, ll);
        *(uint2*)(Bh + r * LSTR + c4) = pack4(hh);
        *(uint2*)(Bl + r * LSTR + c4) = pack4(ll);
    }
    __syncthreads();
    f32x4 acc[4];
#pragma unroll
    for (int p = 0; p < 4; ++p) acc[p] = (f32x4){0.f, 0.f, 0.f, 0.f};
    int mrow = w * 16 + (l & 15);
    int q8 = (l >> 4) * 8;
#pragma unroll
    for (int ks = 0; ks < 2; ++ks) {
        short8 ah = *(const short8*)(Ah + mrow * LSTR + ks * 32 + q8);
        short8 al = *(const short8*)(Al + mrow * LSTR + ks * 32 + q8);
#pragma unroll
        for (int p = 0; p < 4; ++p) {
            int nrow = p * 16 + (l & 15);
            short8 bh = *(const short8*)(Bh + nrow * LSTR + ks * 32 + q8);
            short8 bl = *(const short8*)(Bl + nrow * LSTR + ks * 32 + q8);
            acc[p] = __builtin_amdgcn_mfma_f32_16x16x32_bf16(ah, bh, acc[p], 0, 0, 0);
            acc[p] = __builtin_amdgcn_mfma_f32_16x16x32_bf16(ah, bl, acc[p], 0, 0, 0);
            acc[p] = __builtin_amdgcn_mfma_f32_16x16x32_bf16(al, bh, acc[p], 0, 0, 0);
        }
    }
    int isbf = *flag;
    int q = l >> 4;
#pragma unroll
    for (int p = 0; p < 4; ++p) {
        int col = n0 + p * 16 + (l & 15);
        if (col < NUSER) {
#pragma unroll
            for (int r = 0; r < 4; ++r) {
                int row = m0 + w * 16 + q * 4 + r;
                size_t o = (size_t)row * NUSER + col;
                if (isbf) ((__hip_bfloat16*)out)[o] = __float2bfloat16(acc[p][r]);
                else      ((float*)out)[o] = acc[p][r];
            }
        }
    }
}

extern "C" void kernel_launch(void* const* d_in, const int* in_sizes, int n_in,
                              void* d_out, int out_size, void* d_ws, size_t ws_size,
                              hipStream_t stream) {
    const void* presc = d_in[1];
    const void* emb   = d_in[2];
    const void* W1    = d_in[3];
    const void* b1    = d_in[4];
    const void* W2    = d_in[5];
    const void* b2    = d_in[6];
    const void* mlpW  = d_in[7];
    const void* mlpB  = d_in[8];
    const void* gamma = d_in[9];
    const void* beta  = d_in[10];
    const int* tg = (const int*)d_in[11];
    const int* s1 = (const int*)d_in[12];
    const int* s2 = (const int*)d_in[13];
    float* ws = (float*)d_ws;
    (void)in_sizes; (void)n_in; (void)out_size;

    float* bnsum = ws + OFF_BNS;
    float* cnss  = ws + OFF_CNSS;
    int*   flag  = (int*)(ws + OFF_FLAG);
    float* cvt   = ws + OFF_CVT;
    float* embF  = cvt + CVT_EMB;
    float* W1F   = cvt + CVT_W1;
    float* b1F   = cvt + CVT_B1;
    float* W2F   = cvt + CVT_W2;
    float* b2F   = cvt + CVT_B2;
    float* mlpWF = cvt + CVT_MLPW;
    float* mlpBF = cvt + CVT_MLPB;
    float* gamF  = cvt + CVT_GAMMA;
    float* betF  = cvt + CVT_BETA;
    u16*   Abf   = (u16*)(ws + OFF_ABF);
    float* rcnt  = ws + OFF_RC;
    uint*  P8    = (uint*)(ws + OFF_POOL);
    float* part  = ws + OFF_PART;
    u16*   H1hi  = (u16*)(ws + OFF_H1);
    u16*   H1lo  = H1hi + 64ull * NPAD;
    u16*   H2hi  = (u16*)(ws + OFF_H2);
    u16*   H2lo  = H2hi + 3ull * 64 * NPAD;
    float* out2  = ws + OFF_OUT2;
    float* cu    = ws + OFF_CU;
    float* ci    = ws + OFF_CI;
    float* hpre  = ws + OFF_H;
    u16*   cwh   = (u16*)(ws + OFF_PART);   // aliases dead part buffer
    u16*   cwl   = cwh + 64ull * KPAD;

    size_t p8per = 3ull * NN * P8W;        // u32 words per partial copy
    int S = 4;
    if      (ws_size >= (OFF_POOL + 16ull * p8per) * 4) S = 16;
    else if (ws_size >= (OFF_POOL +  8ull * p8per) * 4) S = 8;
    int HB = 3 * RB * S;
    int CVTB = CVT_TOTAL / 512;            // 174, exact

    // 1: convert U histogram U {zero accum + view0 sumsq}
    k_front<<<HB + 1 + CVTB, 512, 0, stream>>>(presc, emb,
        emb, W1, b1, W2, b2, mlpW, mlpB, gamma, beta,
        tg, s1, s2, cvt, cnss, bnsum, flag, P8, S, HB);
    // 2: histogram merge U layer-1 transform
    k_abf_xf1<<<3 * NN + MT, 256, 0, stream>>>(P8, S, Abf, rcnt,
        embF, W1F, b1F, H1hi, H1lo);
    // 3: layer-1 aggregation
    k_aggp<<<3 * MT * KT, 256, 0, stream>>>(Abf, H1hi, H1lo, 0, part);
    // 4: layer-2 transform (inline partial-combine + tanh)
    k_xf2<<<3 * MT, 256, 0, stream>>>(nullptr, 0, part, rcnt, 1, MT, NN,
        W2F, b2F, H2hi, H2lo, 64ull * NPAD, NPAD);
    // 5: layer-2 aggregation
    k_aggp<<<3 * MT * KT, 256, 0, stream>>>(Abf, H2hi, H2lo, 64ull * NPAD, part);
    // 6: layer-2 combine + col sumsq
    k_comb<<<3 * CPG, 256, 0, stream>>>(part, rcnt, out2, cnss);
    // 7: view fusion
    k_cuci<<<448 + NUSER, 64, 0, stream>>>(embF, out2, cnss, cu, ci);
    // 8: cuWT = cu @ mlpW^T
    k_xf2<<<ENT, 256, 0, stream>>>(cu, 0, nullptr, nullptr, 0, ENT, 448,
        mlpWF, nullptr, cwh, cwl, 0, KPAD);
    // 9: pooling+MLP GEMM (+BN partials)
    k_esynd<<<BB / 64, 256, 0, stream>>>(presc, cwh, cwl, mlpBF, flag, hpre, bnsum);
    // 10: final GEMM
    k_final<<<(BB / 64) * FNT, 256, 0, stream>>>(hpre, bnsum, gamF, betF, ci, d_out, flag);
}

// Round 7
// 197.733 us; speedup vs baseline: 1.1612x; 1.1612x over previous
//
#include <hip/hip_runtime.h>
#include <hip/hip_bf16.h>

// R7: histogram reshaped for balance + occupancy. R6's k_front (50-56us, occ
// 20%, VALUBusy 9%) was latency-bound with unbalanced blocks (tg slices 2x
// sub slices), R=13 scan redundancy, 799 blocks on 512 slots. Now: per-graph
// slice counts (S0=16 tg, S1=8 subs -> all heavy blocks own 62.5K edges),
// ROWS=128 via 76KB dynamic LDS (static-96 fallback), 1024 thr (32 waves/CU),
// grid 408 = one balanced round. Also fixes latent H1-inside-P8-span race:
// H-tail now placed past the P8 extent via runtime offsets.

#define NN    1195
#define NUSER 805
#define NITEM 390
#define DD    64
#define BB    2048
#define NPAD  1216          // 19*64, padded node/k count
#define E_TOT 1000000
#define E_SUB 500000
#define MT    19            // m-tiles per graph
#define KT    8             // K-split factor
#define CHUNK 3             // ceil(19/8) k-subtiles per block
#define LSTR  72            // LDS row stride in bf16 elems
#define OUT2STRIDE (NN*DD)
#define CPG    299          // comb blocks per graph = ceil(1195*64/256)
#define P8W    152          // u32 words per histogram row (1216 u4 cells)
#define FNT    13           // k_final col tiles = ceil(805/64)
#define KPAD   448          // esynd padded K (7*64)
#define ENT    7            // esynd k-steps

typedef unsigned int uint;
typedef unsigned short u16;
typedef unsigned char u8;
typedef __attribute__((ext_vector_type(8))) short short8;
typedef __attribute__((ext_vector_type(4))) float f32x4;

__device__ __forceinline__ float wsum(float v) {
#pragma unroll
    for (int m = 32; m > 0; m >>= 1) v += __shfl_xor(v, m, 64);
    return v;
}
__device__ __forceinline__ u16 f2b(float f) {           // fp32 -> bf16 RNE bits
    uint u = __float_as_uint(f);
    return (u16)((u + 0x7FFFu + ((u >> 16) & 1u)) >> 16);
}
__device__ __forceinline__ float b2f16(u16 b) { return __uint_as_float(((uint)b) << 16); }
__device__ __forceinline__ void split4(const float* v, u16* hh, u16* ll) {
#pragma unroll
    for (int j = 0; j < 4; ++j) {
        u16 h = f2b(v[j]);
        hh[j] = h;
        ll[j] = f2b(v[j] - b2f16(h));
    }
}
__device__ __forceinline__ uint2 pack4(const u16* x) {
    uint2 o;
    o.x = (uint)x[0] | ((uint)x[1] << 16);
    o.y = (uint)x[2] | ((uint)x[3] << 16);
    return o;
}

// ---- converted-input layout (floats, relative to OFF_CVT) ----
#define CVT_EMB   0
#define CVT_W1    76480
#define CVT_B1    80576
#define CVT_W2    80640
#define CVT_B2    84736
#define CVT_MLPW  84800
#define CVT_MLPB  88896
#define CVT_GAMMA 88960
#define CVT_BETA  89024
#define CVT_TOTAL 89088

// ---------------- workspace: static prefix; pool laid out at runtime ----------------
constexpr size_t alignUp64(size_t x) { return (x + 63) & ~size_t(63); }
constexpr size_t OFF_BNS  = 0;                                        // [128]
constexpr size_t OFF_CNSS = 128;                                      // [256]
constexpr size_t OFF_FLAG = 384;                                      // [16]
constexpr size_t OFF_CVT  = 448;                                      // [CVT_TOTAL]
constexpr size_t OFF_ABF  = alignUp64(OFF_CVT + CVT_TOTAL);           // bf16 A 3*NN*NPAD u16
constexpr size_t OFF_RC   = alignUp64(OFF_ABF + (3ull * NN * NPAD) / 2);
constexpr size_t OFF_POOL = alignUp64(OFF_RC + 3ull * NPAD);
// P8 at OFF_POOL ([copies][NN][P8W] u32); part/cwh alias OFF_POOL after P8 dies;
// H1/H2/out2/cu/ci/hpre placed AFTER the P8 extent (k_abf_xf1 writes H1 while
// reading P8 -> must not overlap).

// ---------------- kernels ----------------

// FUSED front: [0,HB) balanced histogram blocks (dynamic LDS, rows x 1216 u4);
// HB = stats block (zero bnsum/cnss + view-0 user col-sumsq from RAW emb);
// (HB, ...] input-convert blocks.
__global__ __launch_bounds__(1024, 8) void k_front(const void* presc, const void* emb,
        const void* p1, const void* p2, const void* p3, const void* p4,
        const void* p5, const void* p6, const void* p7, const void* p8, const void* p9,
        const int* __restrict__ tg, const int* __restrict__ s1, const int* __restrict__ s2,
        float* __restrict__ dst, float* __restrict__ cnss, float* __restrict__ bnsum,
        int* __restrict__ flag, uint* __restrict__ P8,
        int S0, int S1, int R, int rows, int HB) {
    extern __shared__ __align__(16) uint lds[];
    int b = blockIdx.x, t = threadIdx.x;
    int isbf = (((const u16*)presc)[0] == 0x3F80u) ? 1 : 0;   // presc[0][0]==1.0 always
    if (b < HB) {
        // ---- balanced LDS-bucketed u4 partial histogram ----
        int RS0 = R * S0, RS1 = R * S1;
        int g, p, r;
        if (b < RS0)            { g = 0; p = b % S0; r = b / S0; }
        else if (b < RS0 + RS1) { int b2 = b - RS0;        g = 1; p = b2 % S1; r = b2 / S1; }
        else                    { int b3 = b - RS0 - RS1;  g = 2; p = b3 % S1; r = b3 / S1; }
        int Sg = g ? S1 : S0;
        int cb = (g == 0) ? 0 : S0 + (g - 1) * S1;       // copy base
        int r0 = r * rows;
        int nw4 = (rows * P8W) >> 2;
        {
            uint4* l4 = (uint4*)lds;
            for (int i = t; i < nw4; i += 1024) l4[i] = (uint4){0u, 0u, 0u, 0u};
        }
        __syncthreads();
        const int* eg = (g == 0) ? tg : (g == 1 ? s1 : s2);
        int Eg = (g == 0) ? E_TOT : E_SUB;
        int e0 = (int)(((long)p * Eg / Sg) & ~3L);
        int e1 = (p == Sg - 1) ? Eg : (int)(((long)(p + 1) * Eg / Sg) & ~3L);
        const int* srcp = eg;
        const int* dstp = eg + Eg;
        for (int i = e0 + t * 4; i < e1; i += 1024 * 4) {
            int4 d4 = *(const int4*)(dstp + i);
            int4 s4 = *(const int4*)(srcp + i);
            int rw;
            rw = d4.x - r0; if ((unsigned)rw < (unsigned)rows) atomicAdd(&lds[rw * P8W + (s4.x >> 3)], 1u << ((s4.x & 7) * 4));
            rw = d4.y - r0; if ((unsigned)rw < (unsigned)rows) atomicAdd(&lds[rw * P8W + (s4.y >> 3)], 1u << ((s4.y & 7) * 4));
            rw = d4.z - r0; if ((unsigned)rw < (unsigned)rows) atomicAdd(&lds[rw * P8W + (s4.z >> 3)], 1u << ((s4.z & 7) * 4));
            rw = d4.w - r0; if ((unsigned)rw < (unsigned)rows) atomicAdd(&lds[rw * P8W + (s4.w >> 3)], 1u << ((s4.w & 7) * 4));
        }
        __syncthreads();
        int rmax = rows; if (r0 + rmax > NN) rmax = NN - r0;
        uint* out = P8 + ((size_t)(cb + p) * NN + r0) * P8W;
        int n4 = (rmax * P8W) >> 2;
        const uint4* l4 = (const uint4*)lds;
        uint4* o4 = (uint4*)out;
        for (int i = t; i < n4; i += 1024) o4[i] = l4[i];
    } else if (b == HB) {
        // ---- stats block: zero accumulators + view-0 user column sumsq ----
        if (t < 192) cnss[64 + t] = 0.0f;
        if (t < 128) bnsum[t] = 0.0f;
        int c = t & 63, chunk = t >> 6;            // 16 row-chunks
        float s = 0.0f;
        const u16* e16 = (const u16*)emb;
        const float* e32 = (const float*)emb;
        for (int r = chunk; r < NUSER; r += 16) {
            float v = isbf ? b2f16(e16[r * 64 + c]) : e32[r * 64 + c];
            s = fmaf(v, v, s);
        }
        float* sd = (float*)lds;
        sd[t] = s;
        __syncthreads();
        if (t < 64) {
            float tot = 0.0f;
#pragma unroll
            for (int j = 0; j < 16; ++j) tot += sd[j * 64 + t];
            cnss[t] = tot;
        }
    } else {
        // ---- input convert (bf16|f32 -> f32) ----
        int i = (b - HB - 1) * 1024 + t;
        if (i == 0) *flag = isbf;
        if (i < CVT_TOTAL) {
            const void* s2p; int o2;
            if      (i < CVT_W1)    { s2p = p1; o2 = i; }
            else if (i < CVT_B1)    { s2p = p2; o2 = i - CVT_W1; }
            else if (i < CVT_W2)    { s2p = p3; o2 = i - CVT_B1; }
            else if (i < CVT_B2)    { s2p = p4; o2 = i - CVT_W2; }
            else if (i < CVT_MLPW)  { s2p = p5; o2 = i - CVT_B2; }
            else if (i < CVT_MLPB)  { s2p = p6; o2 = i - CVT_MLPW; }
            else if (i < CVT_GAMMA) { s2p = p7; o2 = i - CVT_MLPB; }
            else if (i < CVT_BETA)  { s2p = p8; o2 = i - CVT_GAMMA; }
            else                    { s2p = p9; o2 = i - CVT_BETA; }
            dst[i] = isbf ? __bfloat162float(((const __hip_bfloat16*)s2p)[o2])
                          : ((const float*)s2p)[o2];
        }
    }
}

// shared MFMA transform body: Hout[d][col] = sum_k W[d][k]*x[col][k] (+bias),
// transposed bf16 hi/lo planes. fromPart: x row = tanh(sum_kt part * rcnt).
__device__ __forceinline__ void xf2_body(int g, int n0, int t,
        const float* xsrc, size_t xgstride,
        const float* part, const float* rcnt, int fromPart, int rowlim,
        const float* W, const float* bias,
        u16* Hhi, u16* Hlo, size_t hgstride, int ostride,
        u16* Ah, u16* Al, u16* Bh, u16* Bl, float* bs) {
    int w = t >> 6, l = t & 63;
    if (t < 64) bs[t] = bias ? bias[t] : 0.0f;
    int r = t >> 2, c0 = (t & 3) * 16;
    {
        const float* Wr = W + r * 64 + c0;
        float av[16];
#pragma unroll
        for (int j4 = 0; j4 < 4; ++j4) {
            float4 v = *(const float4*)(Wr + j4 * 4);
            av[j4*4+0] = v.x; av[j4*4+1] = v.y; av[j4*4+2] = v.z; av[j4*4+3] = v.w;
        }
#pragma unroll
        for (int j4 = 0; j4 < 4; ++j4) {
            u16 hh[4], ll[4];
            split4(av + j4*4, hh, ll);
            *(uint2*)(Ah + r * LSTR + c0 + j4*4) = pack4(hh);
            *(uint2*)(Al + r * LSTR + c0 + j4*4) = pack4(ll);
        }
    }
    {
        int node = n0 + r;
        float xr[16];
#pragma unroll
        for (int j = 0; j < 16; ++j) xr[j] = 0.0f;
        if (node < rowlim) {
            if (fromPart) {
#pragma unroll
                for (int k = 0; k < KT; ++k) {
                    const float* pp = part + (((size_t)k * 3 + g) * NPAD + node) * 64 + c0;
#pragma unroll
                    for (int j4 = 0; j4 < 4; ++j4) {
                        float4 v = *(const float4*)(pp + j4 * 4);
                        xr[j4*4+0] += v.x; xr[j4*4+1] += v.y;
                        xr[j4*4+2] += v.z; xr[j4*4+3] += v.w;
                    }
                }
                float rc = rcnt[g * NPAD + node];
#pragma unroll
                for (int j = 0; j < 16; ++j) xr[j] = tanhf(xr[j] * rc);
            } else {
                const float* Xr = xsrc + xgstride * g + (size_t)node * 64 + c0;
#pragma unroll
                for (int j4 = 0; j4 < 4; ++j4) {
                    float4 v = *(const float4*)(Xr + j4 * 4);
                    xr[j4*4+0] = v.x; xr[j4*4+1] = v.y;
                    xr[j4*4+2] = v.z; xr[j4*4+3] = v.w;
                }
            }
        }
#pragma unroll
        for (int j4 = 0; j4 < 4; ++j4) {
            u16 hh[4], ll[4];
            split4(xr + j4*4, hh, ll);
            *(uint2*)(Bh + r * LSTR + c0 + j4*4) = pack4(hh);
            *(uint2*)(Bl + r * LSTR + c0 + j4*4) = pack4(ll);
        }
    }
    __syncthreads();
    f32x4 acc[4];
#pragma unroll
    for (int p = 0; p < 4; ++p) acc[p] = (f32x4){0.f, 0.f, 0.f, 0.f};
    int mrow = w * 16 + (l & 15);
    int q8 = (l >> 4) * 8;
#pragma unroll
    for (int ks = 0; ks < 2; ++ks) {
        short8 ah = *(const short8*)(Ah + mrow * LSTR + ks * 32 + q8);
        short8 al = *(const short8*)(Al + mrow * LSTR + ks * 32 + q8);
#pragma unroll
        for (int p = 0; p < 4; ++p) {
            int nrow = p * 16 + (l & 15);
            short8 bh = *(const short8*)(Bh + nrow * LSTR + ks * 32 + q8);
            short8 bl = *(const short8*)(Bl + nrow * LSTR + ks * 32 + q8);
            acc[p] = __builtin_amdgcn_mfma_f32_16x16x32_bf16(ah, bh, acc[p], 0, 0, 0);
            acc[p] = __builtin_amdgcn_mfma_f32_16x16x32_bf16(ah, bl, acc[p], 0, 0, 0);
            acc[p] = __builtin_amdgcn_mfma_f32_16x16x32_bf16(al, bh, acc[p], 0, 0, 0);
        }
    }
    int q = l >> 4;
#pragma unroll
    for (int p = 0; p < 4; ++p) {
        int node = n0 + p * 16 + (l & 15);
#pragma unroll
        for (int rr2 = 0; rr2 < 4; ++rr2) {
            int d = w * 16 + q * 4 + rr2;
            float v = acc[p][rr2] + bs[d];
            u16 h = f2b(v);
            size_t o = hgstride * g + (size_t)d * ostride + node;
            Hhi[o] = h;
            Hlo[o] = f2b(v - b2f16(h));
        }
    }
}

// standalone xf2 (L2 fromPart; cuWT)
__global__ __launch_bounds__(256) void k_xf2(const float* __restrict__ xsrc,
        size_t xgstride, const float* __restrict__ part, const float* __restrict__ rcnt,
        int fromPart, int ngb, int rowlim,
        const float* __restrict__ W, const float* __restrict__ bias,
        u16* __restrict__ Hhi, u16* __restrict__ Hlo, size_t hgstride, int ostride) {
    __shared__ u16 Ah[64 * LSTR], Al[64 * LSTR], Bh[64 * LSTR], Bl[64 * LSTR];
    __shared__ float bs[64];
    int b = blockIdx.x;
    xf2_body(b / ngb, (b % ngb) * 64, threadIdx.x, xsrc, xgstride, part, rcnt,
             fromPart, rowlim, W, bias, Hhi, Hlo, hgstride, ostride,
             Ah, Al, Bh, Bl, bs);
}

// FUSED: [0,3*NN) = merge per-graph u4 partial histograms -> bf16 A + 1/deg;
// [3*NN, 3*NN+MT) = xf2 layer-1 (emb @ W1^T + b1). Independent work.
__global__ __launch_bounds__(256) void k_abf_xf1(const uint* __restrict__ P8,
        int S0, int S1,
        u16* __restrict__ Abf, float* __restrict__ rcnt,
        const float* __restrict__ embF, const float* __restrict__ W1,
        const float* __restrict__ b1, u16* __restrict__ H1hi, u16* __restrict__ H1lo) {
    __shared__ u16 Ah[64 * LSTR], Al[64 * LSTR], Bh[64 * LSTR], Bl[64 * LSTR];
    __shared__ float bs[64];
    __shared__ float ws4[4];
    int b = blockIdx.x, t = threadIdx.x;
    if (b < 3 * NN) {
        int g = b / NN, m = b % NN;
        int Sg = g ? S1 : S0;
        int cb = (g == 0) ? 0 : S0 + (g - 1) * S1;
        int w = t >> 6;
        float partial = 0.0f;
        if (t < P8W) {
            uint cnt[8] = {0, 0, 0, 0, 0, 0, 0, 0};
            for (int p = 0; p < Sg; ++p) {
                uint v = P8[((size_t)(cb + p) * NN + m) * P8W + t];
#pragma unroll
                for (int k = 0; k < 8; ++k) cnt[k] += (v >> (4 * k)) & 15u;
            }
            uint4 o;
            o.x = (uint)f2b((float)cnt[0]) | ((uint)f2b((float)cnt[1]) << 16);
            o.y = (uint)f2b((float)cnt[2]) | ((uint)f2b((float)cnt[3]) << 16);
            o.z = (uint)f2b((float)cnt[4]) | ((uint)f2b((float)cnt[5]) << 16);
            o.w = (uint)f2b((float)cnt[6]) | ((uint)f2b((float)cnt[7]) << 16);
            *(uint4*)(Abf + (size_t)b * NPAD + t * 8) = o;
#pragma unroll
            for (int k = 0; k < 8; ++k) partial += (float)cnt[k];
        }
        partial = wsum(partial);
        if ((t & 63) == 0) ws4[w] = partial;
        __syncthreads();
        if (t == 0)
            rcnt[g * NPAD + m] = 1.0f / fmaxf(ws4[0] + ws4[1] + ws4[2] + ws4[3], 1.0f);
    } else {
        int nt = b - 3 * NN;
        xf2_body(0, nt * 64, t, embF, 0, nullptr, nullptr, 0, NN, W1, b1,
                 H1hi, H1lo, 0, NPAD, Ah, Al, Bh, Bl, bs);
    }
}

// MFMA aggregation with split-bf16 B; K-split partials
__global__ __launch_bounds__(256) void k_aggp(const u16* __restrict__ Abf,
        const u16* __restrict__ Hhi, const u16* __restrict__ Hlo, size_t hstride,
        float* __restrict__ part) {
    int b = blockIdx.x;
    int kt = b & 7;
    int mt = (b >> 3) % MT;
    int g  = (b >> 3) / MT;
    int t = threadIdx.x, w = t >> 6, l = t & 63;
    __shared__ u16 As[64 * LSTR], Bh[64 * LSTR], Bl[64 * LSTR];
    f32x4 acc[4];
#pragma unroll
    for (int p = 0; p < 4; ++p) acc[p] = (f32x4){0.f, 0.f, 0.f, 0.f};
    int m0 = mt * 64;
    const u16* Ag = Abf + (size_t)g * NN * NPAD;
    const u16* Hg = Hhi + hstride * g;
    const u16* Lg = Hlo + hstride * g;
    int st0 = kt * CHUNK;
    int st1 = st0 + CHUNK; if (st1 > MT) st1 = MT;
    int rr = t >> 4, c4 = (t & 15) * 4;
    for (int st = st0; st < st1; ++st) {
        int s0 = st * 64;
        __syncthreads();
#pragma unroll
        for (int pass = 0; pass < 4; ++pass) {
            int r = pass * 16 + rr;
            uint2 av = {0u, 0u};
            if (m0 + r < NN) av = *(const uint2*)(Ag + (size_t)(m0 + r) * NPAD + s0 + c4);
            *(uint2*)(As + r * LSTR + c4) = av;
            *(uint2*)(Bh + r * LSTR + c4) = *(const uint2*)(Hg + (size_t)r * NPAD + s0 + c4);
            *(uint2*)(Bl + r * LSTR + c4) = *(const uint2*)(Lg + (size_t)r * NPAD + s0 + c4);
        }
        __syncthreads();
        int mrow = w * 16 + (l & 15);
        int q8 = (l >> 4) * 8;
#pragma unroll
        for (int ks = 0; ks < 2; ++ks) {
            short8 a = *(const short8*)(As + mrow * LSTR + ks * 32 + q8);
#pragma unroll
            for (int p = 0; p < 4; ++p) {
                int nrow = p * 16 + (l & 15);
                short8 bh = *(const short8*)(Bh + nrow * LSTR + ks * 32 + q8);
                short8 bl = *(const short8*)(Bl + nrow * LSTR + ks * 32 + q8);
                acc[p] = __builtin_amdgcn_mfma_f32_16x16x32_bf16(a, bh, acc[p], 0, 0, 0);
                acc[p] = __builtin_amdgcn_mfma_f32_16x16x32_bf16(a, bl, acc[p], 0, 0, 0);
            }
        }
    }
    int q = l >> 4;
#pragma unroll
    for (int p = 0; p < 4; ++p) {
        int n = p * 16 + (l & 15);
#pragma unroll
        for (int r = 0; r < 4; ++r) {
            int m = m0 + w * 16 + q * 4 + r;
            if (m < NN)
                part[(((size_t)kt * 3 + g) * NPAD + m) * 64 + n] = acc[p][r];
        }
    }
}

// layer-2 combine + views-1..3 user column sumsq accumulation
__global__ __launch_bounds__(256) void k_comb(const float* __restrict__ part,
        const float* __restrict__ rcnt, float* __restrict__ out, float* __restrict__ cnss) {
    int g = blockIdx.x / CPG, bi = blockIdx.x % CPG;
    int t = threadIdx.x;
    int idx = bi * 256 + t;                 // within graph
    int m = idx >> 6, n = idx & 63;
    bool valid = idx < NN * 64;
    float v = 0.0f;
    if (valid) {
        float s = 0.0f;
#pragma unroll
        for (int k = 0; k < KT; ++k)
            s += part[(((size_t)k * 3 + g) * NPAD + m) * 64 + n];
        v = tanhf(s * rcnt[g * NPAD + m]);
        out[(size_t)g * NN * 64 + idx] = v;
    }
    float x2 = (valid && m < NUSER) ? v * v : 0.0f;
    __shared__ float sd[256];
    sd[t] = x2;
    __syncthreads();
    if (t < 64) {
        float s = sd[t] + sd[t + 64] + sd[t + 128] + sd[t + 192];
        if (s != 0.0f) atomicAdd(&cnss[(g + 1) * 64 + t], s);
    }
}

// cu (item rows, 4-view row-norm fusion) + ci (user rows, 4-view col-norm fusion)
__global__ void k_cuci(const float* __restrict__ embf, const float* __restrict__ out2,
                       const float* __restrict__ cnss, float* __restrict__ cu,
                       float* __restrict__ ci) {
    int b = blockIdx.x, l = threadIdx.x;
    if (b < 448) {
        if (b >= NITEM) { cu[(size_t)b * DD + l] = 0.0f; return; }
        int node = NUSER + b;
        const float* v0 = embf + (size_t)node * DD;
        const float* v1 = out2 + (size_t)node * DD;
        const float* v2 = out2 + OUT2STRIDE + (size_t)node * DD;
        const float* v3 = out2 + 2ull * OUT2STRIDE + (size_t)node * DD;
        float total = 0.0f;
        { float x = v0[l]; float ss = wsum(x * x); total += x / sqrtf(ss); }
        { float x = v1[l]; float ss = wsum(x * x); total += x / sqrtf(ss); }
        { float x = v2[l]; float ss = wsum(x * x); total += x / sqrtf(ss); }
        { float x = v3[l]; float ss = wsum(x * x); total += x / sqrtf(ss); }
        cu[(size_t)b * DD + l] = 0.25f * total;
    } else {
        int u = b - 448;
        size_t i = (size_t)u * DD + l;
        float s = embf[i] / sqrtf(cnss[l])
                + out2[i] / sqrtf(cnss[64 + l])
                + out2[OUT2STRIDE + i] / sqrtf(cnss[128 + l])
                + out2[2ull * OUT2STRIDE + i] / sqrtf(cnss[192 + l]);
        ci[i] = 0.25f * s;
    }
}

// h_pre = (presc @ cuWT^T)/rowsum + bias via MFMA; rowsum from ones-column MFMA;
// + BN partial sums.
__global__ __launch_bounds__(256) void k_esynd(const void* __restrict__ presc,
        const u16* __restrict__ cwh, const u16* __restrict__ cwl,
        const float* __restrict__ mlpB, const int* __restrict__ flag,
        float* __restrict__ hpre, float* __restrict__ bnsum) {
    int m0 = blockIdx.x * 64;
    int t = threadIdx.x, w = t >> 6, l = t & 63;
    int isbf = *flag;
    const u16* pB = (const u16*)presc;
    const float* pF = (const float*)presc;
    __shared__ u16 As[64 * LSTR], Bh[64 * LSTR], Bl[64 * LSTR];
    __shared__ u16 Ones[16 * LSTR];
    __shared__ float bs[64];
    __shared__ float r1[4][64], r2[4][64];
    for (int i = t; i < 16 * LSTR; i += 256) Ones[i] = (i < 64) ? 0x3F80u : 0u;
    if (t < 64) bs[t] = mlpB[t];

    f32x4 acc[4], acc1;
#pragma unroll
    for (int p = 0; p < 4; ++p) acc[p] = (f32x4){0.f, 0.f, 0.f, 0.f};
    acc1 = (f32x4){0.f, 0.f, 0.f, 0.f};

    int rr = t >> 4, c4 = (t & 15) * 4;
    for (int st = 0; st < ENT; ++st) {
        int s0 = st * 64;
        __syncthreads();
#pragma unroll
        for (int pass = 0; pass < 4; ++pass) {
            int r = pass * 16 + rr;
            int m = m0 + r;
            int kb = s0 + c4;
            u16 a4[4];
            if (kb + 3 < NITEM) {
                if (isbf) {
                    const uint* p32 = (const uint*)pB + (((size_t)m * NITEM + kb) >> 1);
                    uint u0 = p32[0], u1 = p32[1];
                    a4[0] = (u16)u0; a4[1] = (u16)(u0 >> 16);
                    a4[2] = (u16)u1; a4[3] = (u16)(u1 >> 16);
                } else {
                    const float2* pf2 = (const float2*)(pF + (size_t)m * NITEM + kb);
                    float2 f0 = pf2[0], f1 = pf2[1];
                    a4[0] = f2b(f0.x); a4[1] = f2b(f0.y);
                    a4[2] = f2b(f1.x); a4[3] = f2b(f1.y);
                }
            } else {
#pragma unroll
                for (int j = 0; j < 4; ++j) {
                    int k = kb + j;
                    a4[j] = (k < NITEM)
                          ? (isbf ? pB[(size_t)m * NITEM + k] : f2b(pF[(size_t)m * NITEM + k]))
                          : (u16)0;
                }
            }
            uint2 o;
            o.x = (uint)a4[0] | ((uint)a4[1] << 16);
            o.y = (uint)a4[2] | ((uint)a4[3] << 16);
            *(uint2*)(As + r * LSTR + c4) = o;
            *(uint2*)(Bh + r * LSTR + c4) = *(const uint2*)(cwh + (size_t)r * KPAD + s0 + c4);
            *(uint2*)(Bl + r * LSTR + c4) = *(const uint2*)(cwl + (size_t)r * KPAD + s0 + c4);
        }
        __syncthreads();
        int mrow = w * 16 + (l & 15);
        int q8 = (l >> 4) * 8;
#pragma unroll
        for (int ks = 0; ks < 2; ++ks) {
            short8 a = *(const short8*)(As + mrow * LSTR + ks * 32 + q8);
            short8 on = *(const short8*)(Ones + (l & 15) * LSTR + ks * 32 + q8);
            acc1 = __builtin_amdgcn_mfma_f32_16x16x32_bf16(a, on, acc1, 0, 0, 0);
#pragma unroll
            for (int p = 0; p < 4; ++p) {
                int nrow = p * 16 + (l & 15);
                short8 bh = *(const short8*)(Bh + nrow * LSTR + ks * 32 + q8);
                short8 bl = *(const short8*)(Bl + nrow * LSTR + ks * 32 + q8);
                acc[p] = __builtin_amdgcn_mfma_f32_16x16x32_bf16(a, bh, acc[p], 0, 0, 0);
                acc[p] = __builtin_amdgcn_mfma_f32_16x16x32_bf16(a, bl, acc[p], 0, 0, 0);
            }
        }
    }
    float inv[4];
#pragma unroll
    for (int r = 0; r < 4; ++r)
        inv[r] = 1.0f / __shfl(acc1[r], l & 48, 64);
    int q = l >> 4;
#pragma unroll
    for (int p = 0; p < 4; ++p) {
        int col = p * 16 + (l & 15);
        float a = 0.0f, c = 0.0f;
#pragma unroll
        for (int r = 0; r < 4; ++r) {
            float hv = acc[p][r] * inv[r] + bs[col];
            hpre[(size_t)(m0 + w * 16 + q * 4 + r) * DD + col] = hv;
            a += hv; c = fmaf(hv, hv, c);
        }
        a += __shfl_xor(a, 16, 64); a += __shfl_xor(a, 32, 64);
        c += __shfl_xor(c, 16, 64); c += __shfl_xor(c, 32, 64);
        if (l < 16) { r1[w][col] = a; r2[w][col] = c; }
    }
    __syncthreads();
    if (t < 64) {
        atomicAdd(&bnsum[t],      r1[0][t] + r1[1][t] + r1[2][t] + r1[3][t]);
        atomicAdd(&bnsum[64 + t], r2[0][t] + r2[1][t] + r2[2][t] + r2[3][t]);
    }
}

// pre = relu(BN(h_pre)) @ ci^T via MFMA 64x64 tiles, bf16 hi/lo both operands.
__global__ __launch_bounds__(256) void k_final(const float* __restrict__ hpre,
        const float* __restrict__ bnsum, const float* __restrict__ gamma,
        const float* __restrict__ beta, const float* __restrict__ ci,
        void* __restrict__ out, const int* __restrict__ flag) {
    int b = blockIdx.x;
    int mt = b / FNT, nt = b % FNT;
    int m0 = mt * 64, n0 = nt * 64;
    int t = threadIdx.x, w = t >> 6, l = t & 63;
    __shared__ u16 Ah[64 * LSTR], Al[64 * LSTR], Bh[64 * LSTR], Bl[64 * LSTR];
    __shared__ float mn[64], rsg[64], bt[64];
    if (t < 64) {
        float mean = bnsum[t] * (1.0f / BB);
        float var = bnsum[64 + t] * (1.0f / BB) - mean * mean;
        mn[t] = mean;
        rsg[t] = gamma[t] / sqrtf(var + 1e-5f);
        bt[t] = beta[t];
    }
    __syncthreads();
    const float4* hp4 = (const float4*)(hpre + (size_t)m0 * 64);
    const float4* ci4 = (const float4*)ci;
#pragma unroll
    for (int k = 0; k < 4; ++k) {
        int i = t + k * 256;
        int r = i >> 4, c4 = (i & 15) * 4;
        float4 v = hp4[i];
        float vv[4] = {v.x, v.y, v.z, v.w};
        u16 hh[4], ll[4];
#pragma unroll
        for (int j = 0; j < 4; ++j) {
            int d = c4 + j;
            float x = fmaxf((vv[j] - mn[d]) * rsg[d] + bt[d], 0.0f);
            u16 hb = f2b(x);
            hh[j] = hb;
            ll[j] = f2b(x - b2f16(hb));
        }
        *(uint2*)(Ah + r * LSTR + c4) = pack4(hh);
        *(uint2*)(Al + r * LSTR + c4) = pack4(ll);
        int col = n0 + r;
        float4 cv = (col < NUSER) ? ci4[(size_t)col * 16 + (i & 15)]
                                  : (float4){0.f, 0.f, 0.f, 0.f};
        float cc[4] = {cv.x, cv.y, cv.z, cv.w};
        split4(cc, hh, ll);
        *(uint2*)(Bh + r * LSTR + c4) = pack4(hh);
        *(uint2*)(Bl + r * LSTR + c4) = pack4(ll);
    }
    __syncthreads();
    f32x4 acc[4];
#pragma unroll
    for (int p = 0; p < 4; ++p) acc[p] = (f32x4){0.f, 0.f, 0.f, 0.f};
    int mrow = w * 16 + (l & 15);
    int q8 = (l >> 4) * 8;
#pragma unroll
    for (int ks = 0; ks < 2; ++ks) {
        short8 ah = *(const short8*)(Ah + mrow * LSTR + ks * 32 + q8);
        short8 al = *(const short8*)(Al + mrow * LSTR + ks * 32 + q8);
#pragma unroll
        for (int p = 0; p < 4; ++p) {
            int nrow = p * 16 + (l & 15);
            short8 bh = *(const short8*)(Bh + nrow * LSTR + ks * 32 + q8);
            short8 bl = *(const short8*)(Bl + nrow * LSTR + ks * 32 + q8);
            acc[p] = __builtin_amdgcn_mfma_f32_16x16x32_bf16(ah, bh, acc[p], 0, 0, 0);
            acc[p] = __builtin_amdgcn_mfma_f32_16x16x32_bf16(ah, bl, acc[p], 0, 0, 0);
            acc[p] = __builtin_amdgcn_mfma_f32_16x16x32_bf16(al, bh, acc[p], 0, 0, 0);
        }
    }
    int isbf = *flag;
    int q = l >> 4;
#pragma unroll
    for (int p = 0; p < 4; ++p) {
        int col = n0 + p * 16 + (l & 15);
        if (col < NUSER) {
#pragma unroll
            for (int r = 0; r < 4; ++r) {
                int row = m0 + w * 16 + q * 4 + r;
                size_t o = (size_t)row * NUSER + col;
                if (isbf) ((__hip_bfloat16*)out)[o] = __float2bfloat16(acc[p][r]);
                else      ((float*)out)[o] = acc[p][r];
            }
        }
    }
}

extern "C" void kernel_launch(void* const* d_in, const int* in_sizes, int n_in,
                              void* d_out, int out_size, void* d_ws, size_t ws_size,
                              hipStream_t stream) {
    const void* presc = d_in[1];
    const void* emb   = d_in[2];
    const void* W1    = d_in[3];
    const void* b1    = d_in[4];
    const void* W2    = d_in[5];
    const void* b2    = d_in[6];
    const void* mlpW  = d_in[7];
    const void* mlpB  = d_in[8];
    const void* gamma = d_in[9];
    const void* beta  = d_in[10];
    const int* tg = (const int*)d_in[11];
    const int* s1 = (const int*)d_in[12];
    const int* s2 = (const int*)d_in[13];
    float* ws = (float*)d_ws;
    (void)in_sizes; (void)n_in; (void)out_size;

    float* bnsum = ws + OFF_BNS;
    float* cnss  = ws + OFF_CNSS;
    int*   flag  = (int*)(ws + OFF_FLAG);
    float* cvt   = ws + OFF_CVT;
    float* embF  = cvt + CVT_EMB;
    float* W1F   = cvt + CVT_W1;
    float* b1F   = cvt + CVT_B1;
    float* W2F   = cvt + CVT_W2;
    float* b2F   = cvt + CVT_B2;
    float* mlpWF = cvt + CVT_MLPW;
    float* mlpBF = cvt + CVT_MLPB;
    float* gamF  = cvt + CVT_GAMMA;
    float* betF  = cvt + CVT_BETA;
    u16*   Abf   = (u16*)(ws + OFF_ABF);
    float* rcnt  = ws + OFF_RC;
    uint*  P8    = (uint*)(ws + OFF_POOL);
    float* part  = ws + OFF_POOL;           // aliases P8 (P8 dead before k_aggp)
    u16*   cwh   = (u16*)(ws + OFF_POOL);   // aliases part (dead before k_xf2-cuW)
    u16*   cwl   = cwh + 64ull * KPAD;

    // one-time: opt into 76KB dynamic LDS (128 histogram rows/block; 2 blk/CU)
    static int g_rows = 0;
    if (g_rows == 0) {
        hipError_t e = hipFuncSetAttribute((const void*)k_front,
                hipFuncAttributeMaxDynamicSharedMemorySize, 128 * P8W * 4);
        g_rows = (e == hipSuccess) ? 128 : 96;
    }
    int rows = g_rows;
    int R = (NN + rows - 1) / rows;

    // slice-unit SU: S0=4*SU (tg), S1=2*SU (each sub) -> equal edges per block
    size_t cpw = (size_t)NN * P8W;          // u32 per histogram copy
    size_t tailF = 760000;                  // H1+H2+out2+cu+ci+hpre floats (+slack)
    int SU = 1;
    if      ((OFF_POOL + 32 * cpw + tailF) * 4 <= ws_size) SU = 4;
    else if ((OFF_POOL + 16 * cpw + tailF) * 4 <= ws_size) SU = 2;
    int S0 = 4 * SU, S1 = 2 * SU;
    int copies = S0 + 2 * S1;

    // pool tail placed AFTER the P8 extent (k_abf_xf1 writes H1 concurrent
    // with P8 reads -> must not overlap)
    size_t o = alignUp64(OFF_POOL + (size_t)copies * cpw);
    u16*   H1hi = (u16*)(ws + o);  u16* H1lo = H1hi + 64ull * NPAD;
    o = alignUp64(o + 64ull * NPAD);                 // 2 planes = 64*NPAD floats
    u16*   H2hi = (u16*)(ws + o);  u16* H2lo = H2hi + 3ull * 64 * NPAD;
    o = alignUp64(o + 3ull * 64 * NPAD);
    float* out2 = ws + o;          o = alignUp64(o + 3ull * NN * DD);
    float* cu   = ws + o;          o = alignUp64(o + 448ull * DD);
    float* ci   = ws + o;          o = alignUp64(o + (size_t)NUSER * DD);
    float* hpre = ws + o;

    int HB = R * copies;
    int CVTB = CVT_TOTAL / 1024;            // 87, exact

    // 1: histogram (balanced) U stats U convert
    k_front<<<HB + 1 + CVTB, 1024, rows * P8W * 4, stream>>>(presc, emb,
        emb, W1, b1, W2, b2, mlpW, mlpB, gamma, beta,
        tg, s1, s2, cvt, cnss, bnsum, flag, P8, S0, S1, R, rows, HB);
    // 2: histogram merge U layer-1 transform
    k_abf_xf1<<<3 * NN + MT, 256, 0, stream>>>(P8, S0, S1, Abf, rcnt,
        embF, W1F, b1F, H1hi, H1lo);
    // 3: layer-1 aggregation
    k_aggp<<<3 * MT * KT, 256, 0, stream>>>(Abf, H1hi, H1lo, 0, part);
    // 4: layer-2 transform (inline partial-combine + tanh)
    k_xf2<<<3 * MT, 256, 0, stream>>>(nullptr, 0, part, rcnt, 1, MT, NN,
        W2F, b2F, H2hi, H2lo, 64ull * NPAD, NPAD);
    // 5: layer-2 aggregation
    k_aggp<<<3 * MT * KT, 256, 0, stream>>>(Abf, H2hi, H2lo, 64ull * NPAD, part);
    // 6: layer-2 combine + col sumsq
    k_comb<<<3 * CPG, 256, 0, stream>>>(part, rcnt, out2, cnss);
    // 7: view fusion
    k_cuci<<<448 + NUSER, 64, 0, stream>>>(embF, out2, cnss, cu, ci);
    // 8: cuWT = cu @ mlpW^T
    k_xf2<<<ENT, 256, 0, stream>>>(cu, 0, nullptr, nullptr, 0, ENT, 448,
        mlpWF, nullptr, cwh, cwl, 0, KPAD);
    // 9: pooling+MLP GEMM (+BN partials)
    k_esynd<<<BB / 64, 256, 0, stream>>>(presc, cwh, cwl, mlpBF, flag, hpre, bnsum);
    // 10: final GEMM
    k_final<<<(BB / 64) * FNT, 256, 0, stream>>>(hpre, bnsum, gamF, betF, ci, d_out, flag);
}